// Round 5
// baseline (287.058 us; speedup 1.0000x reference)
//
#include <hip/hip_runtime.h>

#define N_NODES_C 50000
#define N_EDGES_C 800000
#define IN_FEATS_C 128
#define HEADS_C 8
#define HD_C 256            // HEADS * OUT_FEATS
#define NEG_SLOPE_C 0.2f
#define SCAN_BS 1024
#define SCAN_NBLK ((N_NODES_C + SCAN_BS - 1) / SCAN_BS)   // 49

typedef __attribute__((ext_vector_type(8))) short bf16x8;
typedef __attribute__((ext_vector_type(4))) float floatx4;

__device__ inline unsigned short f2bf(float f) {
  unsigned int u = __float_as_uint(f);
  unsigned int r = (u + 0x7FFFu + ((u >> 16) & 1u)) >> 16;   // RNE
  return (unsigned short)r;
}
__device__ inline float bf2f(unsigned short s) {
  unsigned int u = ((unsigned int)s) << 16;
  return __uint_as_float(u);
}

// ---------------- el/er: exact fp32, proj fused in-block ----------------
// Each block first computes alp[h][k] = sum_d W[h*32+d][k]*attn_l[h][d] into
// LDS (W is L2-resident; 128 KB re-read per block x 512 blocks = 64 MB L2),
// then grid-strides over nodes, wave per node.
__global__ __launch_bounds__(256) void elr_kernel(
    const float* __restrict__ feat, const float* __restrict__ W,
    const float* __restrict__ attn_l, const float* __restrict__ attn_r,
    float* __restrict__ el, float* __restrict__ er) {
  __shared__ float sAl[8 * 132];
  __shared__ float sAr[8 * 132];
  int t = threadIdx.x;
#pragma unroll
  for (int i = 0; i < 4; ++i) {
    int idx = t + i * 256;      // (h,k)
    int h = idx >> 7, k = idx & 127;
    float sl = 0.f, sr = 0.f;
#pragma unroll 8
    for (int d = 0; d < 32; ++d) {
      float w = W[(size_t)(h * 32 + d) * IN_FEATS_C + k];
      sl = fmaf(w, attn_l[h * 32 + d], sl);
      sr = fmaf(w, attn_r[h * 32 + d], sr);
    }
    sAl[h * 132 + k] = sl;
    sAr[h * 132 + k] = sr;
  }
  __syncthreads();

  int wid = t >> 6, lane = t & 63;
  int h = lane >> 3;
  int kb = (lane & 7) * 16;
  const float* al = &sAl[h * 132 + kb];
  const float* ar = &sAr[h * 132 + kb];
  float4 a0 = *(const float4*)(al + 0), a1 = *(const float4*)(al + 4);
  float4 a2 = *(const float4*)(al + 8), a3 = *(const float4*)(al + 12);
  float4 b0 = *(const float4*)(ar + 0), b1 = *(const float4*)(ar + 4);
  float4 b2 = *(const float4*)(ar + 8), b3 = *(const float4*)(ar + 12);

  int stride = gridDim.x * 4;
  for (int node = blockIdx.x * 4 + wid; node < N_NODES_C; node += stride) {
    const float* fr = &feat[(size_t)node * IN_FEATS_C + kb];
    float4 f0 = *(const float4*)(fr + 0);
    float4 f1 = *(const float4*)(fr + 4);
    float4 f2 = *(const float4*)(fr + 8);
    float4 f3 = *(const float4*)(fr + 12);
    float pl = f0.x * a0.x + f0.y * a0.y + f0.z * a0.z + f0.w * a0.w
             + f1.x * a1.x + f1.y * a1.y + f1.z * a1.z + f1.w * a1.w
             + f2.x * a2.x + f2.y * a2.y + f2.z * a2.z + f2.w * a2.w
             + f3.x * a3.x + f3.y * a3.y + f3.z * a3.z + f3.w * a3.w;
    float pr = f0.x * b0.x + f0.y * b0.y + f0.z * b0.z + f0.w * b0.w
             + f1.x * b1.x + f1.y * b1.y + f1.z * b1.z + f1.w * b1.w
             + f2.x * b2.x + f2.y * b2.y + f2.z * b2.z + f2.w * b2.w
             + f3.x * b3.x + f3.y * b3.y + f3.z * b3.z + f3.w * b3.w;
    pl += __shfl_xor(pl, 1); pr += __shfl_xor(pr, 1);
    pl += __shfl_xor(pl, 2); pr += __shfl_xor(pr, 2);
    pl += __shfl_xor(pl, 4); pr += __shfl_xor(pr, 4);
    if ((lane & 7) == 0) {
      el[node * HEADS_C + h] = pl;
      er[node * HEADS_C + h] = pr;
    }
  }
}

// ---------------- MFMA bf16 GEMM: feat_hd_bf = bf16(feat @ W.T) ----------------
// Block: 128 nodes x 128 channels, K=128. A (feat) staged in LDS (34.8 KB);
// B (W) fragments streamed per-ks straight from global (64 KB tile, L1/L2-hot)
// with inline fp32->bf16 convert. Halving LDS doubles resident blocks/CU.
#define LDT 136
__global__ __launch_bounds__(256) void mfma_gemm_kernel(
    const float* __restrict__ feat, const float* __restrict__ W,
    unsigned short* __restrict__ feat_hd_bf) {
  __shared__ unsigned short sA[128 * LDT];     // 34816 B; reused as sOut

  const int bid = blockIdx.x;
  const int nt = bid & 1;              // channel tile
  const int mt = bid >> 1;             // node tile
  const int m0 = mt * 128;
  const int n0 = nt * 128;
  const int t = threadIdx.x;

  // stage A: 128 rows x 32 float4 of feat -> bf16
#pragma unroll
  for (int i = 0; i < 16; ++i) {
    int idx = t + i * 256;
    int row = idx >> 5;
    int c4 = idx & 31;
    int gn = m0 + row;
    float4 v = (gn < N_NODES_C)
                   ? *(const float4*)&feat[(size_t)gn * IN_FEATS_C + c4 * 4]
                   : make_float4(0.f, 0.f, 0.f, 0.f);
    ushort4 b;
    b.x = f2bf(v.x); b.y = f2bf(v.y); b.z = f2bf(v.z); b.w = f2bf(v.w);
    *(ushort4*)&sA[row * LDT + c4 * 4] = b;
  }
  __syncthreads();

  const int wid = t >> 6;
  const int lane = t & 63;
  const int quad = lane >> 4;
  const int l16 = lane & 15;
  const int wm = (wid & 1) * 64;
  const int wn = (wid >> 1) * 64;

  floatx4 acc[4][4];
#pragma unroll
  for (int i = 0; i < 4; ++i)
#pragma unroll
    for (int j = 0; j < 4; ++j) acc[i][j] = (floatx4){0.f, 0.f, 0.f, 0.f};

#pragma unroll
  for (int ks = 0; ks < 4; ++ks) {
    int k0 = ks * 32 + quad * 8;
    // B fragments straight from global W (fp32 -> bf16)
    bf16x8 bfv[4];
#pragma unroll
    for (int n2 = 0; n2 < 4; ++n2) {
      const float* wp = &W[(size_t)(n0 + wn + n2 * 16 + l16) * IN_FEATS_C + k0];
      float4 w0 = *(const float4*)wp;
      float4 w1 = *(const float4*)(wp + 4);
      bf16x8 b;
      b[0] = (short)f2bf(w0.x); b[1] = (short)f2bf(w0.y);
      b[2] = (short)f2bf(w0.z); b[3] = (short)f2bf(w0.w);
      b[4] = (short)f2bf(w1.x); b[5] = (short)f2bf(w1.y);
      b[6] = (short)f2bf(w1.z); b[7] = (short)f2bf(w1.w);
      bfv[n2] = b;
    }
    bf16x8 af[4];
#pragma unroll
    for (int m2 = 0; m2 < 4; ++m2)
      af[m2] = *(const bf16x8*)&sA[(wm + m2 * 16 + l16) * LDT + k0];
#pragma unroll
    for (int m2 = 0; m2 < 4; ++m2)
#pragma unroll
      for (int n2 = 0; n2 < 4; ++n2)
        acc[m2][n2] = __builtin_amdgcn_mfma_f32_16x16x32_bf16(
            af[m2], bfv[n2], acc[m2][n2], 0, 0, 0);
  }

  __syncthreads();   // all waves done reading sA

  // epilogue: D layout col=l16, row=quad*4+reg -> repack via LDS (reuse sA)
#pragma unroll
  for (int m2 = 0; m2 < 4; ++m2)
#pragma unroll
    for (int n2 = 0; n2 < 4; ++n2)
#pragma unroll
      for (int r = 0; r < 4; ++r) {
        int row = wm + m2 * 16 + quad * 4 + r;
        int col = wn + n2 * 16 + l16;
        sA[row * LDT + col] = f2bf(acc[m2][n2][r]);
      }
  __syncthreads();

  // coalesced store: 128 rows x 16 chunks of 8 shorts (16 B)
#pragma unroll
  for (int i = 0; i < 8; ++i) {
    int idx = t + i * 256;
    int row = idx >> 4;
    int ch = idx & 15;
    int gn = m0 + row;
    if (gn < N_NODES_C) {
      *(uint4*)&feat_hd_bf[(size_t)gn * HD_C + n0 + ch * 8] =
          *(const uint4*)&sA[row * LDT + ch * 8];
    }
  }
}

// ---------------- CSR build ----------------
__global__ __launch_bounds__(256) void deg_kernel(
    const int* __restrict__ dst, int* __restrict__ deg) {
  int e = blockIdx.x * 256 + threadIdx.x;
  if (e < N_EDGES_C) atomicAdd(&deg[dst[e]], 1);
}

__global__ __launch_bounds__(SCAN_BS) void scan1_kernel(
    const int* __restrict__ deg, int* __restrict__ row_start,
    int* __restrict__ bsum) {
  __shared__ int s[SCAN_BS];
  int b = blockIdx.x, t = threadIdx.x;
  int i = b * SCAN_BS + t;
  int v = (i < N_NODES_C) ? deg[i] : 0;
  s[t] = v;
  __syncthreads();
#pragma unroll
  for (int off = 1; off < SCAN_BS; off <<= 1) {
    int add = (t >= off) ? s[t - off] : 0;
    __syncthreads();
    s[t] += add;
    __syncthreads();
  }
  if (i < N_NODES_C) row_start[i] = s[t];
  if (t == SCAN_BS - 1) bsum[b] = s[t];
}

// scan2 folded in: first wave re-scans the 49 block sums into LDS, then
// row_start goes inclusive -> exclusive + block offset.
__global__ __launch_bounds__(256) void scan3_kernel(
    const int* __restrict__ deg, const int* __restrict__ bsum,
    int* __restrict__ row_start) {
  __shared__ int sboff[64];
  int t = threadIdx.x;
  if (t < 64) {
    int own = (t < SCAN_NBLK) ? bsum[t] : 0;
    int v = own;
#pragma unroll
    for (int off = 1; off < 64; off <<= 1) {
      int u = __shfl_up(v, off);
      if (t >= off) v += u;
    }
    sboff[t] = v - own;   // exclusive
  }
  __syncthreads();
  int i = blockIdx.x * 256 + threadIdx.x;
  if (i < N_NODES_C) row_start[i] = row_start[i] - deg[i] + sboff[i >> 10];
}

__global__ __launch_bounds__(256) void scatter_kernel(
    const int* __restrict__ src, const int* __restrict__ dst,
    const int* __restrict__ row_start, int* __restrict__ cursor,
    int* __restrict__ csr_src) {
  int e = blockIdx.x * 256 + threadIdx.x;
  if (e >= N_EDGES_C) return;
  int d = dst[e];
  int pos = atomicAdd(&cursor[d], 1);
  csr_src[row_start[d] + pos] = src[e];
}

// ---------------- aggregation over CSR: wave per dst node ----------------
// 8-edge batches: lane h*8+j computes exp only for edge i+j of its own head,
// weights redistributed via shuffle (1 exp per lane per 8 edges).
__global__ __launch_bounds__(256) void agg_csr_kernel(
    const unsigned short* __restrict__ feat_hd_bf, const float* __restrict__ el,
    const float* __restrict__ er, const int* __restrict__ row_start,
    const int* __restrict__ deg, const int* __restrict__ csr_src,
    float* __restrict__ out) {
  int gid = blockIdx.x * 256 + threadIdx.x;
  int node = gid >> 6;
  int lane = threadIdx.x & 63;
  if (node >= N_NODES_C) return;
  int h = lane >> 3;
  int hbase = lane & 56;               // h*8
  int c = lane * 4;
  float er_d = er[node * HEADS_C + h];
  int rs = row_start[node];
  int dg = deg[node];
  float4 acc = make_float4(0.f, 0.f, 0.f, 0.f);
  float zsum = 0.f;

  int i = 0;
  for (; i + 8 <= dg; i += 8) {
    // my weight edge
    int smine = csr_src[rs + i + (lane & 7)];
    float x = el[smine * HEADS_C + h] + er_d;
    x = x > 0.f ? x : NEG_SLOPE_C * x;
    float w = __expf(x);
    // 8 src indices (wave-uniform addresses) + 8 feature gathers in flight
    int s0 = csr_src[rs + i + 0];
    int s1 = csr_src[rs + i + 1];
    int s2 = csr_src[rs + i + 2];
    int s3 = csr_src[rs + i + 3];
    int s4 = csr_src[rs + i + 4];
    int s5 = csr_src[rs + i + 5];
    int s6 = csr_src[rs + i + 6];
    int s7 = csr_src[rs + i + 7];
    ushort4 f0 = *(const ushort4*)&feat_hd_bf[(size_t)s0 * HD_C + c];
    ushort4 f1 = *(const ushort4*)&feat_hd_bf[(size_t)s1 * HD_C + c];
    ushort4 f2 = *(const ushort4*)&feat_hd_bf[(size_t)s2 * HD_C + c];
    ushort4 f3 = *(const ushort4*)&feat_hd_bf[(size_t)s3 * HD_C + c];
    ushort4 f4 = *(const ushort4*)&feat_hd_bf[(size_t)s4 * HD_C + c];
    ushort4 f5 = *(const ushort4*)&feat_hd_bf[(size_t)s5 * HD_C + c];
    ushort4 f6 = *(const ushort4*)&feat_hd_bf[(size_t)s6 * HD_C + c];
    ushort4 f7 = *(const ushort4*)&feat_hd_bf[(size_t)s7 * HD_C + c];
    float w0 = __shfl(w, hbase + 0);
    float w1 = __shfl(w, hbase + 1);
    float w2 = __shfl(w, hbase + 2);
    float w3 = __shfl(w, hbase + 3);
    float w4 = __shfl(w, hbase + 4);
    float w5 = __shfl(w, hbase + 5);
    float w6 = __shfl(w, hbase + 6);
    float w7 = __shfl(w, hbase + 7);
    zsum += ((w0 + w1) + (w2 + w3)) + ((w4 + w5) + (w6 + w7));
    acc.x = fmaf(w0, bf2f(f0.x), acc.x); acc.y = fmaf(w0, bf2f(f0.y), acc.y);
    acc.z = fmaf(w0, bf2f(f0.z), acc.z); acc.w = fmaf(w0, bf2f(f0.w), acc.w);
    acc.x = fmaf(w1, bf2f(f1.x), acc.x); acc.y = fmaf(w1, bf2f(f1.y), acc.y);
    acc.z = fmaf(w1, bf2f(f1.z), acc.z); acc.w = fmaf(w1, bf2f(f1.w), acc.w);
    acc.x = fmaf(w2, bf2f(f2.x), acc.x); acc.y = fmaf(w2, bf2f(f2.y), acc.y);
    acc.z = fmaf(w2, bf2f(f2.z), acc.z); acc.w = fmaf(w2, bf2f(f2.w), acc.w);
    acc.x = fmaf(w3, bf2f(f3.x), acc.x); acc.y = fmaf(w3, bf2f(f3.y), acc.y);
    acc.z = fmaf(w3, bf2f(f3.z), acc.z); acc.w = fmaf(w3, bf2f(f3.w), acc.w);
    acc.x = fmaf(w4, bf2f(f4.x), acc.x); acc.y = fmaf(w4, bf2f(f4.y), acc.y);
    acc.z = fmaf(w4, bf2f(f4.z), acc.z); acc.w = fmaf(w4, bf2f(f4.w), acc.w);
    acc.x = fmaf(w5, bf2f(f5.x), acc.x); acc.y = fmaf(w5, bf2f(f5.y), acc.y);
    acc.z = fmaf(w5, bf2f(f5.z), acc.z); acc.w = fmaf(w5, bf2f(f5.w), acc.w);
    acc.x = fmaf(w6, bf2f(f6.x), acc.x); acc.y = fmaf(w6, bf2f(f6.y), acc.y);
    acc.z = fmaf(w6, bf2f(f6.z), acc.z); acc.w = fmaf(w6, bf2f(f6.w), acc.w);
    acc.x = fmaf(w7, bf2f(f7.x), acc.x); acc.y = fmaf(w7, bf2f(f7.y), acc.y);
    acc.z = fmaf(w7, bf2f(f7.z), acc.z); acc.w = fmaf(w7, bf2f(f7.w), acc.w);
  }
  for (; i < dg; ++i) {
    int s = csr_src[rs + i];
    float x = el[s * HEADS_C + h] + er_d;
    x = x > 0.f ? x : NEG_SLOPE_C * x;
    float w = __expf(x);
    zsum += w;
    ushort4 f = *(const ushort4*)&feat_hd_bf[(size_t)s * HD_C + c];
    acc.x = fmaf(w, bf2f(f.x), acc.x);
    acc.y = fmaf(w, bf2f(f.y), acc.y);
    acc.z = fmaf(w, bf2f(f.z), acc.z);
    acc.w = fmaf(w, bf2f(f.w), acc.w);
  }

  float inv = (dg > 0) ? 1.f / zsum : 0.f;
  acc.x *= inv; acc.y *= inv; acc.z *= inv; acc.w *= inv;
  *(float4*)&out[(size_t)node * HD_C + c] = acc;
}

extern "C" void kernel_launch(void* const* d_in, const int* in_sizes, int n_in,
                              void* d_out, int out_size, void* d_ws, size_t ws_size,
                              hipStream_t stream) {
  const float* feat   = (const float*)d_in[0];
  const float* W      = (const float*)d_in[1];
  const float* attn_l = (const float*)d_in[2];
  const float* attn_r = (const float*)d_in[3];
  const int* src      = (const int*)d_in[4];
  const int* dst      = (const int*)d_in[5];
  float* out = (float*)d_out;

  char* ws = (char*)d_ws;
  unsigned short* feat_hd_bf = (unsigned short*)ws;  ws += (size_t)N_NODES_C * HD_C * 2;     // 25.6 MB
  float* el      = (float*)ws;                       ws += (size_t)N_NODES_C * HEADS_C * 4;  // 1.6 MB
  float* er      = (float*)ws;                       ws += (size_t)N_NODES_C * HEADS_C * 4;  // 1.6 MB
  int* deg       = (int*)ws;                         ws += (size_t)N_NODES_C * 4;
  int* cursor    = (int*)ws;                         ws += (size_t)N_NODES_C * 4;  // adjacent to deg: one memset
  int* row_start = (int*)ws;                         ws += (size_t)N_NODES_C * 4;
  int* bsum      = (int*)ws;                         ws += 64 * 4;
  int* csr_src   = (int*)ws;                         ws += (size_t)N_EDGES_C * 4;            // 3.2 MB

  hipMemsetAsync(deg, 0, (size_t)N_NODES_C * 2 * 4, stream);   // deg + cursor

  int m_tiles = (N_NODES_C + 127) / 128;   // 391
  mfma_gemm_kernel<<<m_tiles * 2, 256, 0, stream>>>(feat, W, feat_hd_bf);

  elr_kernel<<<512, 256, 0, stream>>>(feat, W, attn_l, attn_r, el, er);

  deg_kernel<<<(N_EDGES_C + 255) / 256, 256, 0, stream>>>(dst, deg);
  scan1_kernel<<<SCAN_NBLK, SCAN_BS, 0, stream>>>(deg, row_start, bsum);
  scan3_kernel<<<(N_NODES_C + 255) / 256, 256, 0, stream>>>(deg, bsum, row_start);
  scatter_kernel<<<(N_EDGES_C + 255) / 256, 256, 0, stream>>>(src, dst, row_start, cursor, csr_src);

  agg_csr_kernel<<<(N_NODES_C + 3) / 4, 256, 0, stream>>>(
      feat_hd_bf, el, er, row_start, deg, csr_src, out);
}

// Round 7
// 279.575 us; speedup vs baseline: 1.0268x; 1.0268x over previous
//
#include <hip/hip_runtime.h>

#define N_NODES_C 50000
#define N_EDGES_C 800000
#define IN_FEATS_C 128
#define HEADS_C 8
#define HD_C 256            // HEADS * OUT_FEATS
#define NEG_SLOPE_C 0.2f
#define SCAN_BS 1024
#define SCAN_NBLK 49        // ceil(50000/1024)
#define LDT 136             // LDS row stride in shorts (272 B, 16B-aligned)

#define GEMM_BLOCKS 782     // ceil(50000/128) * 2 channel tiles
#define DEG_BLOCKS 80
#define K1_GRID 1024        // gemm 0..781 | deg 782..861 | elr 862..1023

typedef __attribute__((ext_vector_type(8))) short bf16x8;
typedef __attribute__((ext_vector_type(4))) float floatx4;

__device__ inline unsigned short f2bf(float f) {
  unsigned int u = __float_as_uint(f);
  unsigned int r = (u + 0x7FFFu + ((u >> 16) & 1u)) >> 16;   // RNE
  return (unsigned short)r;
}
__device__ inline float bf2f(unsigned short s) {
  unsigned int u = ((unsigned int)s) << 16;
  return __uint_as_float(u);
}

// 49-entry exclusive scan of bsum into sboff[64] (first wave only, then barrier)
__device__ inline void boff_scan(const int* __restrict__ bsum, int* sboff) {
  int t = threadIdx.x;
  if (t < 64) {
    int own = (t < SCAN_NBLK) ? bsum[t] : 0;
    int v = own;
#pragma unroll
    for (int off = 1; off < 64; off <<= 1) {
      int u = __shfl_up(v, off);
      if (t >= off) v += u;
    }
    sboff[t] = v - own;   // exclusive
  }
  __syncthreads();
}

// ============ K1: gemm (0..781) || deg (782..861) || elr (862..1023) ============
// All three are mutually independent (gemm writes feat_hd_bf; deg histograms dst;
// elr reads feat/W only) -> one launch, no sync needed.
__global__ __launch_bounds__(256) void front_kernel(
    const float* __restrict__ feat, const float* __restrict__ W,
    const float* __restrict__ attn_l, const float* __restrict__ attn_r,
    const int* __restrict__ dst,
    unsigned short* __restrict__ feat_hd_bf,
    float* __restrict__ el, float* __restrict__ er,
    int* __restrict__ deg) {
  __shared__ __align__(16) unsigned char smem_raw[128 * LDT * 2];  // 34816 B
  const int bid = blockIdx.x;
  const int t = threadIdx.x;

  if (bid < GEMM_BLOCKS) {
    // ---- MFMA bf16 GEMM tile: 128 nodes x 128 channels, K=128 ----
    unsigned short* sA = (unsigned short*)smem_raw;
    const int nt = bid & 1;
    const int mt = bid >> 1;
    const int m0 = mt * 128;
    const int n0 = nt * 128;

#pragma unroll
    for (int i = 0; i < 16; ++i) {
      int idx = t + i * 256;
      int row = idx >> 5;
      int c4 = idx & 31;
      int gn = m0 + row;
      float4 v = (gn < N_NODES_C)
                     ? *(const float4*)&feat[(size_t)gn * IN_FEATS_C + c4 * 4]
                     : make_float4(0.f, 0.f, 0.f, 0.f);
      ushort4 b;
      b.x = f2bf(v.x); b.y = f2bf(v.y); b.z = f2bf(v.z); b.w = f2bf(v.w);
      *(ushort4*)&sA[row * LDT + c4 * 4] = b;
    }
    __syncthreads();

    const int wid = t >> 6;
    const int lane = t & 63;
    const int quad = lane >> 4;
    const int l16 = lane & 15;
    const int wm = (wid & 1) * 64;
    const int wn = (wid >> 1) * 64;

    floatx4 acc[4][4];
#pragma unroll
    for (int i = 0; i < 4; ++i)
#pragma unroll
      for (int j = 0; j < 4; ++j) acc[i][j] = (floatx4){0.f, 0.f, 0.f, 0.f};

#pragma unroll
    for (int ks = 0; ks < 4; ++ks) {
      int k0 = ks * 32 + quad * 8;
      bf16x8 bfv[4];
#pragma unroll
      for (int n2 = 0; n2 < 4; ++n2) {
        const float* wp = &W[(size_t)(n0 + wn + n2 * 16 + l16) * IN_FEATS_C + k0];
        float4 w0 = *(const float4*)wp;
        float4 w1 = *(const float4*)(wp + 4);
        bf16x8 b;
        b[0] = (short)f2bf(w0.x); b[1] = (short)f2bf(w0.y);
        b[2] = (short)f2bf(w0.z); b[3] = (short)f2bf(w0.w);
        b[4] = (short)f2bf(w1.x); b[5] = (short)f2bf(w1.y);
        b[6] = (short)f2bf(w1.z); b[7] = (short)f2bf(w1.w);
        bfv[n2] = b;
      }
      bf16x8 af[4];
#pragma unroll
      for (int m2 = 0; m2 < 4; ++m2)
        af[m2] = *(const bf16x8*)&sA[(wm + m2 * 16 + l16) * LDT + k0];
#pragma unroll
      for (int m2 = 0; m2 < 4; ++m2)
#pragma unroll
        for (int n2 = 0; n2 < 4; ++n2)
          acc[m2][n2] = __builtin_amdgcn_mfma_f32_16x16x32_bf16(
              af[m2], bfv[n2], acc[m2][n2], 0, 0, 0);
    }
    __syncthreads();

    // epilogue: D layout col=l16, row=quad*4+reg -> repack via LDS
#pragma unroll
    for (int m2 = 0; m2 < 4; ++m2)
#pragma unroll
      for (int n2 = 0; n2 < 4; ++n2)
#pragma unroll
        for (int r = 0; r < 4; ++r) {
          int row = wm + m2 * 16 + quad * 4 + r;
          int col = wn + n2 * 16 + l16;
          sA[row * LDT + col] = f2bf(acc[m2][n2][r]);
        }
    __syncthreads();

#pragma unroll
    for (int i = 0; i < 8; ++i) {
      int idx = t + i * 256;
      int row = idx >> 4;
      int ch = idx & 15;
      int gn = m0 + row;
      if (gn < N_NODES_C) {
        *(uint4*)&feat_hd_bf[(size_t)gn * HD_C + n0 + ch * 8] =
            *(const uint4*)&sA[row * LDT + ch * 8];
      }
    }
  } else if (bid < GEMM_BLOCKS + DEG_BLOCKS) {
    // ---- degree histogram ----
    for (int e = (bid - GEMM_BLOCKS) * 256 + t; e < N_EDGES_C;
         e += DEG_BLOCKS * 256)
      atomicAdd(&deg[dst[e]], 1);
  } else {
    // ---- elr: exact fp32 logits; per-block proj of attn through W ----
    float* sAl = (float*)smem_raw;                 // 8*132 floats
    float* sAr = ((float*)smem_raw) + 8 * 132;
#pragma unroll
    for (int i = 0; i < 4; ++i) {
      int idx = t + i * 256;      // (h,k)
      int h = idx >> 7, k = idx & 127;
      float sl = 0.f, sr = 0.f;
#pragma unroll 8
      for (int d = 0; d < 32; ++d) {
        float w = W[(size_t)(h * 32 + d) * IN_FEATS_C + k];
        sl = fmaf(w, attn_l[h * 32 + d], sl);
        sr = fmaf(w, attn_r[h * 32 + d], sr);
      }
      sAl[h * 132 + k] = sl;
      sAr[h * 132 + k] = sr;
    }
    __syncthreads();

    int wid = t >> 6, lane = t & 63;
    int h = lane >> 3;
    int kb = (lane & 7) * 16;
    const float* al = &sAl[h * 132 + kb];
    const float* ar = &sAr[h * 132 + kb];
    float4 a0 = *(const float4*)(al + 0), a1 = *(const float4*)(al + 4);
    float4 a2 = *(const float4*)(al + 8), a3 = *(const float4*)(al + 12);
    float4 b0 = *(const float4*)(ar + 0), b1 = *(const float4*)(ar + 4);
    float4 b2 = *(const float4*)(ar + 8), b3 = *(const float4*)(ar + 12);

    const int nb = K1_GRID - GEMM_BLOCKS - DEG_BLOCKS;   // 162
    int stride = nb * 4;
    for (int node = (bid - GEMM_BLOCKS - DEG_BLOCKS) * 4 + wid; node < N_NODES_C;
         node += stride) {
      const float* fr = &feat[(size_t)node * IN_FEATS_C + kb];
      float4 f0 = *(const float4*)(fr + 0);
      float4 f1 = *(const float4*)(fr + 4);
      float4 f2 = *(const float4*)(fr + 8);
      float4 f3 = *(const float4*)(fr + 12);
      float pl = f0.x * a0.x + f0.y * a0.y + f0.z * a0.z + f0.w * a0.w
               + f1.x * a1.x + f1.y * a1.y + f1.z * a1.z + f1.w * a1.w
               + f2.x * a2.x + f2.y * a2.y + f2.z * a2.z + f2.w * a2.w
               + f3.x * a3.x + f3.y * a3.y + f3.z * a3.z + f3.w * a3.w;
      float pr = f0.x * b0.x + f0.y * b0.y + f0.z * b0.z + f0.w * b0.w
               + f1.x * b1.x + f1.y * b1.y + f1.z * b1.z + f1.w * b1.w
               + f2.x * b2.x + f2.y * b2.y + f2.z * b2.z + f2.w * b2.w
               + f3.x * b3.x + f3.y * b3.y + f3.z * b3.z + f3.w * b3.w;
      pl += __shfl_xor(pl, 1); pr += __shfl_xor(pr, 1);
      pl += __shfl_xor(pl, 2); pr += __shfl_xor(pr, 2);
      pl += __shfl_xor(pl, 4); pr += __shfl_xor(pr, 4);
      if ((lane & 7) == 0) {
        el[node * HEADS_C + h] = pl;
        er[node * HEADS_C + h] = pr;
      }
    }
  }
}

// ============ scan1: block-wise inclusive scan of deg ============
__global__ __launch_bounds__(SCAN_BS) void scan1_kernel(
    const int* __restrict__ deg, int* __restrict__ row_start,
    int* __restrict__ bsum) {
  __shared__ int s[SCAN_BS];
  int b = blockIdx.x, t = threadIdx.x;
  int i = b * SCAN_BS + t;
  int v = (i < N_NODES_C) ? deg[i] : 0;
  s[t] = v;
  __syncthreads();
#pragma unroll
  for (int off = 1; off < SCAN_BS; off <<= 1) {
    int add = (t >= off) ? s[t - off] : 0;
    __syncthreads();
    s[t] += add;
    __syncthreads();
  }
  if (i < N_NODES_C) row_start[i] = s[t];   // inclusive
  if (t == SCAN_BS - 1) bsum[b] = s[t];
}

// ============ scatter: absolute CSR position computed inline ============
// pos = (row_start_incl[d] - deg[d] + boff[d>>10]) + cursor[d]++   (cursor 0-seeded)
__global__ __launch_bounds__(256) void scatter_kernel(
    const int* __restrict__ src, const int* __restrict__ dst,
    const int* __restrict__ row_start, const int* __restrict__ deg,
    const int* __restrict__ bsum, int* __restrict__ cursor,
    int* __restrict__ csr_src) {
  __shared__ int sboff[64];
  boff_scan(bsum, sboff);
  int e = blockIdx.x * 256 + threadIdx.x;
  if (e >= N_EDGES_C) return;
  int d = dst[e];
  int rsf = row_start[d] - deg[d] + sboff[d >> 10];
  int pos = rsf + atomicAdd(&cursor[d], 1);
  csr_src[pos] = src[e];
}

// ============ aggregation over CSR: wave per dst node ============
__global__ __launch_bounds__(256) void agg_csr_kernel(
    const unsigned short* __restrict__ feat_hd_bf, const float* __restrict__ el,
    const float* __restrict__ er, const int* __restrict__ row_start,
    const int* __restrict__ deg, const int* __restrict__ bsum,
    const int* __restrict__ csr_src, float* __restrict__ out) {
  __shared__ int sboff[64];
  boff_scan(bsum, sboff);
  int gid = blockIdx.x * 256 + threadIdx.x;
  int node = gid >> 6;
  int lane = threadIdx.x & 63;
  if (node >= N_NODES_C) return;
  int h = lane >> 3;
  int hbase = lane & 56;               // h*8
  int c = lane * 4;
  float er_d = er[node * HEADS_C + h];
  int dg = deg[node];
  int rs = row_start[node] - dg + sboff[node >> 10];
  float4 acc = make_float4(0.f, 0.f, 0.f, 0.f);
  float zsum = 0.f;

  int i = 0;
  for (; i + 8 <= dg; i += 8) {
    int smine = csr_src[rs + i + (lane & 7)];
    float x = el[smine * HEADS_C + h] + er_d;
    x = x > 0.f ? x : NEG_SLOPE_C * x;
    float w = __expf(x);
    int s0 = csr_src[rs + i + 0];
    int s1 = csr_src[rs + i + 1];
    int s2 = csr_src[rs + i + 2];
    int s3 = csr_src[rs + i + 3];
    int s4 = csr_src[rs + i + 4];
    int s5 = csr_src[rs + i + 5];
    int s6 = csr_src[rs + i + 6];
    int s7 = csr_src[rs + i + 7];
    ushort4 f0 = *(const ushort4*)&feat_hd_bf[(size_t)s0 * HD_C + c];
    ushort4 f1 = *(const ushort4*)&feat_hd_bf[(size_t)s1 * HD_C + c];
    ushort4 f2 = *(const ushort4*)&feat_hd_bf[(size_t)s2 * HD_C + c];
    ushort4 f3 = *(const ushort4*)&feat_hd_bf[(size_t)s3 * HD_C + c];
    ushort4 f4 = *(const ushort4*)&feat_hd_bf[(size_t)s4 * HD_C + c];
    ushort4 f5 = *(const ushort4*)&feat_hd_bf[(size_t)s5 * HD_C + c];
    ushort4 f6 = *(const ushort4*)&feat_hd_bf[(size_t)s6 * HD_C + c];
    ushort4 f7 = *(const ushort4*)&feat_hd_bf[(size_t)s7 * HD_C + c];
    float w0 = __shfl(w, hbase + 0);
    float w1 = __shfl(w, hbase + 1);
    float w2 = __shfl(w, hbase + 2);
    float w3 = __shfl(w, hbase + 3);
    float w4 = __shfl(w, hbase + 4);
    float w5 = __shfl(w, hbase + 5);
    float w6 = __shfl(w, hbase + 6);
    float w7 = __shfl(w, hbase + 7);
    zsum += ((w0 + w1) + (w2 + w3)) + ((w4 + w5) + (w6 + w7));
    acc.x = fmaf(w0, bf2f(f0.x), acc.x); acc.y = fmaf(w0, bf2f(f0.y), acc.y);
    acc.z = fmaf(w0, bf2f(f0.z), acc.z); acc.w = fmaf(w0, bf2f(f0.w), acc.w);
    acc.x = fmaf(w1, bf2f(f1.x), acc.x); acc.y = fmaf(w1, bf2f(f1.y), acc.y);
    acc.z = fmaf(w1, bf2f(f1.z), acc.z); acc.w = fmaf(w1, bf2f(f1.w), acc.w);
    acc.x = fmaf(w2, bf2f(f2.x), acc.x); acc.y = fmaf(w2, bf2f(f2.y), acc.y);
    acc.z = fmaf(w2, bf2f(f2.z), acc.z); acc.w = fmaf(w2, bf2f(f2.w), acc.w);
    acc.x = fmaf(w3, bf2f(f3.x), acc.x); acc.y = fmaf(w3, bf2f(f3.y), acc.y);
    acc.z = fmaf(w3, bf2f(f3.z), acc.z); acc.w = fmaf(w3, bf2f(f3.w), acc.w);
    acc.x = fmaf(w4, bf2f(f4.x), acc.x); acc.y = fmaf(w4, bf2f(f4.y), acc.y);
    acc.z = fmaf(w4, bf2f(f4.z), acc.z); acc.w = fmaf(w4, bf2f(f4.w), acc.w);
    acc.x = fmaf(w5, bf2f(f5.x), acc.x); acc.y = fmaf(w5, bf2f(f5.y), acc.y);
    acc.z = fmaf(w5, bf2f(f5.z), acc.z); acc.w = fmaf(w5, bf2f(f5.w), acc.w);
    acc.x = fmaf(w6, bf2f(f6.x), acc.x); acc.y = fmaf(w6, bf2f(f6.y), acc.y);
    acc.z = fmaf(w6, bf2f(f6.z), acc.z); acc.w = fmaf(w6, bf2f(f6.w), acc.w);
    acc.x = fmaf(w7, bf2f(f7.x), acc.x); acc.y = fmaf(w7, bf2f(f7.y), acc.y);
    acc.z = fmaf(w7, bf2f(f7.z), acc.z); acc.w = fmaf(w7, bf2f(f7.w), acc.w);
  }
  for (; i < dg; ++i) {
    int s = csr_src[rs + i];
    float x = el[s * HEADS_C + h] + er_d;
    x = x > 0.f ? x : NEG_SLOPE_C * x;
    float w = __expf(x);
    zsum += w;
    ushort4 f = *(const ushort4*)&feat_hd_bf[(size_t)s * HD_C + c];
    acc.x = fmaf(w, bf2f(f.x), acc.x);
    acc.y = fmaf(w, bf2f(f.y), acc.y);
    acc.z = fmaf(w, bf2f(f.z), acc.z);
    acc.w = fmaf(w, bf2f(f.w), acc.w);
  }

  float inv = (dg > 0) ? 1.f / zsum : 0.f;
  acc.x *= inv; acc.y *= inv; acc.z *= inv; acc.w *= inv;
  *(float4*)&out[(size_t)node * HD_C + c] = acc;
}

extern "C" void kernel_launch(void* const* d_in, const int* in_sizes, int n_in,
                              void* d_out, int out_size, void* d_ws, size_t ws_size,
                              hipStream_t stream) {
  const float* feat   = (const float*)d_in[0];
  const float* W      = (const float*)d_in[1];
  const float* attn_l = (const float*)d_in[2];
  const float* attn_r = (const float*)d_in[3];
  const int* src      = (const int*)d_in[4];
  const int* dst      = (const int*)d_in[5];
  float* out = (float*)d_out;

  char* ws = (char*)d_ws;
  unsigned short* feat_hd_bf = (unsigned short*)ws;  ws += (size_t)N_NODES_C * HD_C * 2;     // 25.6 MB
  float* el      = (float*)ws;                       ws += (size_t)N_NODES_C * HEADS_C * 4;  // 1.6 MB
  float* er      = (float*)ws;                       ws += (size_t)N_NODES_C * HEADS_C * 4;  // 1.6 MB
  int* deg       = (int*)ws;                         ws += (size_t)N_NODES_C * 4;
  int* cursor    = (int*)ws;                         ws += (size_t)N_NODES_C * 4;  // adjacent to deg: one memset
  int* row_start = (int*)ws;                         ws += (size_t)N_NODES_C * 4;
  int* bsum      = (int*)ws;                         ws += 64 * 4;
  int* csr_src   = (int*)ws;                         ws += (size_t)N_EDGES_C * 4;            // 3.2 MB

  hipMemsetAsync(deg, 0, (size_t)N_NODES_C * 2 * 4, stream);   // deg + cursor

  front_kernel<<<K1_GRID, 256, 0, stream>>>(feat, W, attn_l, attn_r, dst,
                                            feat_hd_bf, el, er, deg);

  scan1_kernel<<<SCAN_NBLK, SCAN_BS, 0, stream>>>(deg, row_start, bsum);

  scatter_kernel<<<(N_EDGES_C + 255) / 256, 256, 0, stream>>>(
      src, dst, row_start, deg, bsum, cursor, csr_src);

  agg_csr_kernel<<<(N_NODES_C + 3) / 4, 256, 0, stream>>>(
      feat_hd_bf, el, er, row_start, deg, bsum, csr_src, out);
}

// Round 8
// 257.628 us; speedup vs baseline: 1.1142x; 1.0852x over previous
//
#include <hip/hip_runtime.h>

#define N_NODES_C 50000
#define N_EDGES_C 800000
#define IN_FEATS_C 128
#define HEADS_C 8
#define HD_C 256            // HEADS * OUT_FEATS
#define NEG_SLOPE_C 0.2f
#define SCAN_NBLK 49        // ceil(50000/1024)
#define LDT 136             // LDS row stride in shorts (272 B = 17*16, 16B-aligned)

#define GEMM_BLOCKS 782     // ceil(50000/128) * 2 channel tiles
#define DEG_BLOCKS 242
#define K1_GRID (GEMM_BLOCKS + DEG_BLOCKS)   // 1024

typedef __attribute__((ext_vector_type(8))) short bf16x8;
typedef __attribute__((ext_vector_type(4))) float floatx4;

__device__ inline unsigned short f2bf(float f) {
  unsigned int u = __float_as_uint(f);
  unsigned int r = (u + 0x7FFFu + ((u >> 16) & 1u)) >> 16;   // RNE
  return (unsigned short)r;
}
__device__ inline float bf2f(unsigned short s) {
  unsigned int u = ((unsigned int)s) << 16;
  return __uint_as_float(u);
}

// 49-entry exclusive scan of bsum into sboff[64] (first wave only, then barrier)
__device__ inline void boff_scan(const int* __restrict__ bsum, int* sboff) {
  int t = threadIdx.x;
  if (t < 64) {
    int own = (t < SCAN_NBLK) ? bsum[t] : 0;
    int v = own;
#pragma unroll
    for (int off = 1; off < 64; off <<= 1) {
      int u = __shfl_up(v, off);
      if (t >= off) v += u;
    }
    sboff[t] = v - own;   // exclusive
  }
  __syncthreads();
}

// ============ K1: MFMA gemm + fused el/er (0..781) || deg (782..1023) ============
// gemm block: 128 nodes x 128 channels (= 4 complete heads), K=128.
// el/er computed in-epilogue from the repacked bf16 tile in LDS (no elr pass).
__global__ __launch_bounds__(256) void front_kernel(
    const float* __restrict__ feat, const float* __restrict__ W,
    const float* __restrict__ attn_l, const float* __restrict__ attn_r,
    const int* __restrict__ dst,
    unsigned short* __restrict__ feat_hd_bf,
    float* __restrict__ el, float* __restrict__ er,
    int* __restrict__ deg) {
  __shared__ __align__(16) unsigned short sA[128 * LDT];   // 34816 B; reused as sOut
  __shared__ float sAttnL[128];
  __shared__ float sAttnR[128];
  const int bid = blockIdx.x;
  const int t = threadIdx.x;

  if (bid >= GEMM_BLOCKS) {
    // ---- degree histogram ----
    for (int e = (bid - GEMM_BLOCKS) * 256 + t; e < N_EDGES_C;
         e += DEG_BLOCKS * 256)
      atomicAdd(&deg[dst[e]], 1);
    return;
  }

  const int nt = bid & 1;              // channel tile (heads nt*4 .. nt*4+3)
  const int mt = bid >> 1;
  const int m0 = mt * 128;
  const int n0 = nt * 128;

  // stage attn slices for this tile's 128 channels
  if (t < 128) {
    sAttnL[t] = attn_l[n0 + t];
    sAttnR[t] = attn_r[n0 + t];
  }
  // stage A: 128 rows x 32 float4 of feat -> bf16
#pragma unroll
  for (int i = 0; i < 16; ++i) {
    int idx = t + i * 256;
    int row = idx >> 5;
    int c4 = idx & 31;
    int gn = m0 + row;
    float4 v = (gn < N_NODES_C)
                   ? *(const float4*)&feat[(size_t)gn * IN_FEATS_C + c4 * 4]
                   : make_float4(0.f, 0.f, 0.f, 0.f);
    ushort4 b;
    b.x = f2bf(v.x); b.y = f2bf(v.y); b.z = f2bf(v.z); b.w = f2bf(v.w);
    *(ushort4*)&sA[row * LDT + c4 * 4] = b;
  }
  __syncthreads();

  const int wid = t >> 6;
  const int lane = t & 63;
  const int quad = lane >> 4;
  const int l16 = lane & 15;
  const int wm = (wid & 1) * 64;
  const int wn = (wid >> 1) * 64;

  floatx4 acc[4][4];
#pragma unroll
  for (int i = 0; i < 4; ++i)
#pragma unroll
    for (int j = 0; j < 4; ++j) acc[i][j] = (floatx4){0.f, 0.f, 0.f, 0.f};

#pragma unroll
  for (int ks = 0; ks < 4; ++ks) {
    int k0 = ks * 32 + quad * 8;
    bf16x8 bfv[4];
#pragma unroll
    for (int n2 = 0; n2 < 4; ++n2) {
      const float* wp = &W[(size_t)(n0 + wn + n2 * 16 + l16) * IN_FEATS_C + k0];
      float4 w0 = *(const float4*)wp;
      float4 w1 = *(const float4*)(wp + 4);
      bf16x8 b;
      b[0] = (short)f2bf(w0.x); b[1] = (short)f2bf(w0.y);
      b[2] = (short)f2bf(w0.z); b[3] = (short)f2bf(w0.w);
      b[4] = (short)f2bf(w1.x); b[5] = (short)f2bf(w1.y);
      b[6] = (short)f2bf(w1.z); b[7] = (short)f2bf(w1.w);
      bfv[n2] = b;
    }
    bf16x8 af[4];
#pragma unroll
    for (int m2 = 0; m2 < 4; ++m2)
      af[m2] = *(const bf16x8*)&sA[(wm + m2 * 16 + l16) * LDT + k0];
#pragma unroll
    for (int m2 = 0; m2 < 4; ++m2)
#pragma unroll
      for (int n2 = 0; n2 < 4; ++n2)
        acc[m2][n2] = __builtin_amdgcn_mfma_f32_16x16x32_bf16(
            af[m2], bfv[n2], acc[m2][n2], 0, 0, 0);
  }
  __syncthreads();

  // epilogue: D layout col=l16, row=quad*4+reg -> repack via LDS
#pragma unroll
  for (int m2 = 0; m2 < 4; ++m2)
#pragma unroll
    for (int n2 = 0; n2 < 4; ++n2)
#pragma unroll
      for (int r = 0; r < 4; ++r) {
        int row = wm + m2 * 16 + quad * 4 + r;
        int col = wn + n2 * 16 + l16;
        sA[row * LDT + col] = f2bf(acc[m2][n2][r]);
      }
  __syncthreads();

  // coalesced store of the bf16 tile
#pragma unroll
  for (int i = 0; i < 8; ++i) {
    int idx = t + i * 256;
    int row = idx >> 4;
    int ch = idx & 15;
    int gn = m0 + row;
    if (gn < N_NODES_C) {
      *(uint4*)&feat_hd_bf[(size_t)gn * HD_C + n0 + ch * 8] =
          *(const uint4*)&sA[row * LDT + ch * 8];
    }
  }

  // fused el/er: thread t -> row t>>1, head-pair t&1 (2 heads x 32 ch)
  {
    int row = t >> 1;
    int hh = t & 1;
    int gn = m0 + row;
    if (gn < N_NODES_C) {
      const unsigned short* pr = &sA[row * LDT + hh * 64];
      const float* al = &sAttnL[hh * 64];
      const float* ar = &sAttnR[hh * 64];
      float el0 = 0.f, el1 = 0.f, er0 = 0.f, er1 = 0.f;
#pragma unroll
      for (int d = 0; d < 32; ++d) {
        float v0 = bf2f(pr[d]);
        float v1 = bf2f(pr[32 + d]);
        el0 = fmaf(v0, al[d], el0);
        er0 = fmaf(v0, ar[d], er0);
        el1 = fmaf(v1, al[32 + d], el1);
        er1 = fmaf(v1, ar[32 + d], er1);
      }
      int gh = nt * 4 + hh * 2;
      el[gn * HEADS_C + gh + 0] = el0;
      el[gn * HEADS_C + gh + 1] = el1;
      er[gn * HEADS_C + gh + 0] = er0;
      er[gn * HEADS_C + gh + 1] = er1;
    }
  }
}

// ============ scan1: 256 threads x 4 elements, block-wise inclusive scan ============
__global__ __launch_bounds__(256) void scan1_kernel(
    const int* __restrict__ deg, int* __restrict__ row_start,
    int* __restrict__ bsum) {
  __shared__ int s[256];
  int b = blockIdx.x, t = threadIdx.x;
  int i0 = b * 1024 + t * 4;
  int d0 = 0, d1 = 0, d2 = 0, d3 = 0;
  if (i0 + 4 <= N_NODES_C) {
    int4 d = *(const int4*)&deg[i0];
    d0 = d.x; d1 = d.y; d2 = d.z; d3 = d.w;
  } else {
    if (i0 + 0 < N_NODES_C) d0 = deg[i0 + 0];
    if (i0 + 1 < N_NODES_C) d1 = deg[i0 + 1];
    if (i0 + 2 < N_NODES_C) d2 = deg[i0 + 2];
    if (i0 + 3 < N_NODES_C) d3 = deg[i0 + 3];
  }
  int l1 = d0, l2 = l1 + d1, l3 = l2 + d2, l4 = l3 + d3;
  s[t] = l4;
  __syncthreads();
#pragma unroll
  for (int off = 1; off < 256; off <<= 1) {
    int add = (t >= off) ? s[t - off] : 0;
    __syncthreads();
    s[t] += add;
    __syncthreads();
  }
  int excl = s[t] - l4;
  if (i0 + 0 < N_NODES_C) row_start[i0 + 0] = excl + l1;   // inclusive
  if (i0 + 1 < N_NODES_C) row_start[i0 + 1] = excl + l2;
  if (i0 + 2 < N_NODES_C) row_start[i0 + 2] = excl + l3;
  if (i0 + 3 < N_NODES_C) row_start[i0 + 3] = excl + l4;
  if (t == 255) bsum[b] = s[255];
}

// ============ scatter: absolute CSR position computed inline ============
__global__ __launch_bounds__(256) void scatter_kernel(
    const int* __restrict__ src, const int* __restrict__ dst,
    const int* __restrict__ row_start, const int* __restrict__ deg,
    const int* __restrict__ bsum, int* __restrict__ cursor,
    int* __restrict__ csr_src) {
  __shared__ int sboff[64];
  boff_scan(bsum, sboff);
  int e = blockIdx.x * 256 + threadIdx.x;
  if (e >= N_EDGES_C) return;
  int d = dst[e];
  int rsf = row_start[d] - deg[d] + sboff[d >> 10];
  int pos = rsf + atomicAdd(&cursor[d], 1);
  csr_src[pos] = src[e];
}

// ============ aggregation over CSR: wave per dst node ============
__global__ __launch_bounds__(256) void agg_csr_kernel(
    const unsigned short* __restrict__ feat_hd_bf, const float* __restrict__ el,
    const float* __restrict__ er, const int* __restrict__ row_start,
    const int* __restrict__ deg, const int* __restrict__ bsum,
    const int* __restrict__ csr_src, float* __restrict__ out) {
  __shared__ int sboff[64];
  boff_scan(bsum, sboff);
  int gid = blockIdx.x * 256 + threadIdx.x;
  int node = gid >> 6;
  int lane = threadIdx.x & 63;
  if (node >= N_NODES_C) return;
  int h = lane >> 3;
  int hbase = lane & 56;               // h*8
  int c = lane * 4;
  float er_d = er[node * HEADS_C + h];
  int dg = deg[node];
  int rs = row_start[node] - dg + sboff[node >> 10];
  float4 acc = make_float4(0.f, 0.f, 0.f, 0.f);
  float zsum = 0.f;

  int i = 0;
  for (; i + 8 <= dg; i += 8) {
    int smine = csr_src[rs + i + (lane & 7)];
    float x = el[smine * HEADS_C + h] + er_d;
    x = x > 0.f ? x : NEG_SLOPE_C * x;
    float w = __expf(x);
    int s0 = csr_src[rs + i + 0];
    int s1 = csr_src[rs + i + 1];
    int s2 = csr_src[rs + i + 2];
    int s3 = csr_src[rs + i + 3];
    int s4 = csr_src[rs + i + 4];
    int s5 = csr_src[rs + i + 5];
    int s6 = csr_src[rs + i + 6];
    int s7 = csr_src[rs + i + 7];
    ushort4 f0 = *(const ushort4*)&feat_hd_bf[(size_t)s0 * HD_C + c];
    ushort4 f1 = *(const ushort4*)&feat_hd_bf[(size_t)s1 * HD_C + c];
    ushort4 f2 = *(const ushort4*)&feat_hd_bf[(size_t)s2 * HD_C + c];
    ushort4 f3 = *(const ushort4*)&feat_hd_bf[(size_t)s3 * HD_C + c];
    ushort4 f4 = *(const ushort4*)&feat_hd_bf[(size_t)s4 * HD_C + c];
    ushort4 f5 = *(const ushort4*)&feat_hd_bf[(size_t)s5 * HD_C + c];
    ushort4 f6 = *(const ushort4*)&feat_hd_bf[(size_t)s6 * HD_C + c];
    ushort4 f7 = *(const ushort4*)&feat_hd_bf[(size_t)s7 * HD_C + c];
    float w0 = __shfl(w, hbase + 0);
    float w1 = __shfl(w, hbase + 1);
    float w2 = __shfl(w, hbase + 2);
    float w3 = __shfl(w, hbase + 3);
    float w4 = __shfl(w, hbase + 4);
    float w5 = __shfl(w, hbase + 5);
    float w6 = __shfl(w, hbase + 6);
    float w7 = __shfl(w, hbase + 7);
    zsum += ((w0 + w1) + (w2 + w3)) + ((w4 + w5) + (w6 + w7));
    acc.x = fmaf(w0, bf2f(f0.x), acc.x); acc.y = fmaf(w0, bf2f(f0.y), acc.y);
    acc.z = fmaf(w0, bf2f(f0.z), acc.z); acc.w = fmaf(w0, bf2f(f0.w), acc.w);
    acc.x = fmaf(w1, bf2f(f1.x), acc.x); acc.y = fmaf(w1, bf2f(f1.y), acc.y);
    acc.z = fmaf(w1, bf2f(f1.z), acc.z); acc.w = fmaf(w1, bf2f(f1.w), acc.w);
    acc.x = fmaf(w2, bf2f(f2.x), acc.x); acc.y = fmaf(w2, bf2f(f2.y), acc.y);
    acc.z = fmaf(w2, bf2f(f2.z), acc.z); acc.w = fmaf(w2, bf2f(f2.w), acc.w);
    acc.x = fmaf(w3, bf2f(f3.x), acc.x); acc.y = fmaf(w3, bf2f(f3.y), acc.y);
    acc.z = fmaf(w3, bf2f(f3.z), acc.z); acc.w = fmaf(w3, bf2f(f3.w), acc.w);
    acc.x = fmaf(w4, bf2f(f4.x), acc.x); acc.y = fmaf(w4, bf2f(f4.y), acc.y);
    acc.z = fmaf(w4, bf2f(f4.z), acc.z); acc.w = fmaf(w4, bf2f(f4.w), acc.w);
    acc.x = fmaf(w5, bf2f(f5.x), acc.x); acc.y = fmaf(w5, bf2f(f5.y), acc.y);
    acc.z = fmaf(w5, bf2f(f5.z), acc.z); acc.w = fmaf(w5, bf2f(f5.w), acc.w);
    acc.x = fmaf(w6, bf2f(f6.x), acc.x); acc.y = fmaf(w6, bf2f(f6.y), acc.y);
    acc.z = fmaf(w6, bf2f(f6.z), acc.z); acc.w = fmaf(w6, bf2f(f6.w), acc.w);
    acc.x = fmaf(w7, bf2f(f7.x), acc.x); acc.y = fmaf(w7, bf2f(f7.y), acc.y);
    acc.z = fmaf(w7, bf2f(f7.z), acc.z); acc.w = fmaf(w7, bf2f(f7.w), acc.w);
  }
  for (; i < dg; ++i) {
    int s = csr_src[rs + i];
    float x = el[s * HEADS_C + h] + er_d;
    x = x > 0.f ? x : NEG_SLOPE_C * x;
    float w = __expf(x);
    zsum += w;
    ushort4 f = *(const ushort4*)&feat_hd_bf[(size_t)s * HD_C + c];
    acc.x = fmaf(w, bf2f(f.x), acc.x);
    acc.y = fmaf(w, bf2f(f.y), acc.y);
    acc.z = fmaf(w, bf2f(f.z), acc.z);
    acc.w = fmaf(w, bf2f(f.w), acc.w);
  }

  float inv = (dg > 0) ? 1.f / zsum : 0.f;
  acc.x *= inv; acc.y *= inv; acc.z *= inv; acc.w *= inv;
  *(float4*)&out[(size_t)node * HD_C + c] = acc;
}

extern "C" void kernel_launch(void* const* d_in, const int* in_sizes, int n_in,
                              void* d_out, int out_size, void* d_ws, size_t ws_size,
                              hipStream_t stream) {
  const float* feat   = (const float*)d_in[0];
  const float* W      = (const float*)d_in[1];
  const float* attn_l = (const float*)d_in[2];
  const float* attn_r = (const float*)d_in[3];
  const int* src      = (const int*)d_in[4];
  const int* dst      = (const int*)d_in[5];
  float* out = (float*)d_out;

  char* ws = (char*)d_ws;
  unsigned short* feat_hd_bf = (unsigned short*)ws;  ws += (size_t)N_NODES_C * HD_C * 2;     // 25.6 MB
  float* el      = (float*)ws;                       ws += (size_t)N_NODES_C * HEADS_C * 4;  // 1.6 MB
  float* er      = (float*)ws;                       ws += (size_t)N_NODES_C * HEADS_C * 4;  // 1.6 MB
  int* deg       = (int*)ws;                         ws += (size_t)N_NODES_C * 4;
  int* cursor    = (int*)ws;                         ws += (size_t)N_NODES_C * 4;  // adjacent to deg: one memset
  int* row_start = (int*)ws;                         ws += (size_t)N_NODES_C * 4;
  int* bsum      = (int*)ws;                         ws += 64 * 4;
  int* csr_src   = (int*)ws;                         ws += (size_t)N_EDGES_C * 4;            // 3.2 MB

  hipMemsetAsync(deg, 0, (size_t)N_NODES_C * 2 * 4, stream);   // deg + cursor

  front_kernel<<<K1_GRID, 256, 0, stream>>>(feat, W, attn_l, attn_r, dst,
                                            feat_hd_bf, el, er, deg);

  scan1_kernel<<<SCAN_NBLK, 256, 0, stream>>>(deg, row_start, bsum);

  scatter_kernel<<<(N_EDGES_C + 255) / 256, 256, 0, stream>>>(
      src, dst, row_start, deg, bsum, cursor, csr_src);

  agg_csr_kernel<<<(N_NODES_C + 3) / 4, 256, 0, stream>>>(
      feat_hd_bf, el, er, row_start, deg, bsum, csr_src, out);
}